// Round 6
// baseline (28895.929 us; speedup 1.0000x reference)
//
#include <hip/hip_runtime.h>
#include <math.h>

// Problem constants
#define Vv 8000
#define Ee 256
#define Hh 256
#define Tt 4
#define Bb 64
#define Ss 512

#define EPROJ_PER_DIR (Vv * 1024)   // 8,192,000 floats per direction
#define WMAT_PER_DIR  (Ee * 1024)   // 262,144 floats per direction

__device__ __forceinline__ float sigm(float x) { return 1.f / (1.f + expf(-x)); }

typedef _Float16 half2v __attribute__((ext_vector_type(2)));

__device__ __forceinline__ float fdot2u(unsigned int a, unsigned int b, float c) {
    half2v ha = __builtin_bit_cast(half2v, a);
    half2v hb = __builtin_bit_cast(half2v, b);
#if __has_builtin(__builtin_amdgcn_fdot2)
    return __builtin_amdgcn_fdot2(ha, hb, c, false);
#else
    return c + (float)ha[0] * (float)hb[0] + (float)ha[1] * (float)hb[1];
#endif
}

// ---------------------------------------------------------------------------
// prep: repack weights.
//   WihP [dir][e][j']  j' = u*4+g <-> gate-row g*256+u     (GEMM B-matrix)
//   W16p [dir][us][kp][u_loc][g] u32 = f16x2 over k-pairs  (recurrent, LDS image)
//   bP   [dir][j']
//   WlinQ[dir][u][t] float4/u = Wlin[t][dir*256+u]         (emission)
// ---------------------------------------------------------------------------
__global__ void prep_kernel(const float* __restrict__ Wih_f, const float* __restrict__ Whh_f,
                            const float* __restrict__ b_f,
                            const float* __restrict__ Wih_b, const float* __restrict__ Whh_b,
                            const float* __restrict__ b_b,
                            const float* __restrict__ Wlin,
                            float* __restrict__ WihP, unsigned int* __restrict__ W16p,
                            float* __restrict__ bP, float* __restrict__ WlinQ)
{
    int tid = blockIdx.x * blockDim.x + threadIdx.x;   // [0, 2*262144)
    int dir = tid >> 18;
    int r   = tid & 262143;
    int k   = r >> 10;        // 0..255
    int jp  = r & 1023;       // j'
    int u   = jp >> 2;
    int g   = jp & 3;
    int row = g * 256 + u;    // original gate row
    const float* Wih = dir ? Wih_b : Wih_f;
    const float* Whh = dir ? Whh_b : Whh_f;
    const float* bv  = dir ? b_b   : b_f;
    WihP[dir * WMAT_PER_DIR + k * 1024 + jp] = Wih[row * 256 + k];
    if (!(k & 1)) {
        int kp = k >> 1;                 // 0..127
        int us = u >> 6, u_loc = u & 63;
        union { _Float16 h[2]; unsigned int u32; } pk;
        pk.h[0] = (_Float16)Whh[row * 256 + k];
        pk.h[1] = (_Float16)Whh[row * 256 + k + 1];
        W16p[(((dir * 4 + us) * 128 + kp) * 64 + u_loc) * 4 + g] = pk.u32;
    }
    if (r < 1024) {
        bP[dir * 1024 + jp] = bv[row];
        int uu = r >> 2, tt = r & 3;
        WlinQ[(dir * 256 + uu) * 4 + tt] = Wlin[tt * (2 * Hh) + dir * 256 + uu];
    }
}

// ---------------------------------------------------------------------------
// embproj GEMM: embproj[dir][v][j'] = sum_e emb[v][e]*WihP[dir][e][j'] + bP[dir][j']
// ---------------------------------------------------------------------------
#define BM 64
#define BN 128
#define BK 16
__global__ __launch_bounds__(256) void embproj_gemm(const float* __restrict__ emb,
                                                    const float* __restrict__ WihP,
                                                    const float* __restrict__ bP,
                                                    float* __restrict__ embproj)
{
    int dir = blockIdx.z;
    const float* Bmat = WihP + dir * WMAT_PER_DIR;
    float* C = embproj + (size_t)dir * EPROJ_PER_DIR;
    int m0 = blockIdx.x * BM;
    int n0 = blockIdx.y * BN;

    __shared__ float As[BK][BM];
    __shared__ float Bs[BK][BN];

    int t = threadIdx.x;
    int tm = (t & 15) * 4;
    int tn = (t >> 4) * 8;
    float acc[4][8];
    #pragma unroll
    for (int i = 0; i < 4; ++i)
        #pragma unroll
        for (int j = 0; j < 8; ++j) acc[i][j] = 0.f;

    for (int k0 = 0; k0 < Ee; k0 += BK) {
        {   // A tile 64x16
            int row = t >> 2, seg = t & 3;
            float4 a4 = *(const float4*)(&emb[(size_t)(m0 + row) * Ee + k0 + seg * 4]);
            As[seg * 4 + 0][row] = a4.x;
            As[seg * 4 + 1][row] = a4.y;
            As[seg * 4 + 2][row] = a4.z;
            As[seg * 4 + 3][row] = a4.w;
        }
        {   // B tile 16x128
            int kk = t >> 4, nn = (t & 15) * 8;
            float4 b0 = *(const float4*)(&Bmat[(size_t)(k0 + kk) * 1024 + n0 + nn]);
            float4 b1 = *(const float4*)(&Bmat[(size_t)(k0 + kk) * 1024 + n0 + nn + 4]);
            *(float4*)&Bs[kk][nn]     = b0;
            *(float4*)&Bs[kk][nn + 4] = b1;
        }
        __syncthreads();
        #pragma unroll
        for (int k = 0; k < BK; ++k) {
            float4 a  = *(const float4*)&As[k][tm];
            float4 b0 = *(const float4*)&Bs[k][tn];
            float4 b1 = *(const float4*)&Bs[k][tn + 4];
            float av[4] = {a.x, a.y, a.z, a.w};
            float bv[8] = {b0.x, b0.y, b0.z, b0.w, b1.x, b1.y, b1.z, b1.w};
            #pragma unroll
            for (int i = 0; i < 4; ++i)
                #pragma unroll
                for (int j = 0; j < 8; ++j)
                    acc[i][j] += av[i] * bv[j];
        }
        __syncthreads();
    }
    #pragma unroll
    for (int i = 0; i < 4; ++i) {
        int m = m0 + tm + i;
        #pragma unroll
        for (int j = 0; j < 8; j += 4) {
            float4 o;
            o.x = acc[i][j + 0] + bP[dir * 1024 + n0 + tn + j + 0];
            o.y = acc[i][j + 1] + bP[dir * 1024 + n0 + tn + j + 1];
            o.z = acc[i][j + 2] + bP[dir * 1024 + n0 + tn + j + 2];
            o.w = acc[i][j + 3] + bP[dir * 1024 + n0 + tn + j + 3];
            *(float4*)&C[(size_t)m * 1024 + n0 + tn + j] = o;
        }
    }
}

// ---------------------------------------------------------------------------
// LSTM recurrence, weights fully LDS-resident (no VGPR-residency gamble).
// 64 teams = dir(2) x batch-pair(32); 4 WGs/team, us = quarter of 64 units.
// grid 256 x 512, 1 WG/CU (133KB LDS), cooperative. bx = us*64 + team keeps
// the 4 team members on one XCD (bx % 8 == team % 8, round-robin dispatch).
//   thread: u_loc = tid>>3 (unit in quarter), kq2 = tid&7 (32-k slice).
//   Per step: dot over own 32 k's for 2 batches from LDS weights (128KB read,
//   shared across batches in-register); 8-way shfl reduce -> part LDS;
//   act waves 0/1 (batch A/B): gates+c+h, fused emission (tag partials),
//   pack h f16x2 -> LDS (own quarter) + global hg + RELEASE flag.
//   Consumers: threads whose k-slice maps to peer quarter p poll flags[p]
//   (acquire) then read hg; own-quarter threads never touch global.
//   2 barriers/step. h exchange = 3x2x128B/step through same-XCD L2.
// ---------------------------------------------------------------------------
__global__ void lstm_lds_kernel(
    const int* __restrict__ sentence,
    const float* __restrict__ embproj,
    const unsigned int* __restrict__ W16p,
    const float* __restrict__ WlinQ,
    unsigned int* __restrict__ hg,
    int* __restrict__ flags,
    float* __restrict__ emisP)
{
    extern __shared__ char smem[];
    uint4*        LW4     = (uint4*)smem;                       // 128 KB weights
    unsigned int* h16loc  = (unsigned int*)(smem + 131072);     // [bat][par][32] u32
    float*        part    = (float*)(smem + 131584);            // [bat][64][4] f32

    const int bx   = blockIdx.x;
    const int us   = bx >> 6;          // 0..3
    const int team = bx & 63;          // members bx = team, team+64, ... same XCD
    const int dir  = team >> 5;
    const int bg   = team & 31;
    const int b0   = bg * 2;
    const int tid  = threadIdx.x;
    const int u_loc = tid >> 3;        // 0..63
    const int kq2   = tid & 7;         // 0..7  (32-k slice)
    const int wave  = tid >> 6;
    const int lane  = tid & 63;
    const int p     = kq2 >> 1;        // producer quarter of this k-slice
    const int half  = kq2 & 1;
    const int kp0   = kq2 << 4;        // first k-pair of slice

    // ---- stage this WG's 128KB weight slice into LDS ----
    {
        const uint4* Wsrc = (const uint4*)(W16p + ((size_t)(dir * 4 + us) << 15));
        #pragma unroll
        for (int i = 0; i < 16; ++i)
            LW4[i * 512 + tid] = Wsrc[i * 512 + tid];
    }

    const float* EP = embproj + (size_t)dir * EPROJ_PER_DIR;
    const int fl_base = team * 8;
    unsigned int* hgT = hg + (size_t)team * 512;   // [us][par][bat][32] u32

    // act-wave persistent state (waves 0/1 only)
    const int bat = wave;              // meaningful for wave<2
    const int b = b0 + (wave < 2 ? bat : 0);
    const int* sent = sentence + (size_t)b * Ss;
    float c = 0.f;
    float4 wl = make_float4(0.f, 0.f, 0.f, 0.f);
    float4 ep = make_float4(0.f, 0.f, 0.f, 0.f);
    const int uact = us * 64 + lane;
    if (wave < 2) {
        wl = *(const float4*)&WlinQ[(dir * 256 + uact) * 4];
        const int pos0 = dir ? (Ss - 1) : 0;
        ep = *(const float4*)(EP + (size_t)sent[pos0] * 1024 + uact * 4);
    }
    const int di = us * 2 + dir;       // emission partial buffer index
    long budget = 200000000;           // bounded spin: wrong answer, not hang

    __syncthreads();   // weights staged, h16loc not yet needed (s=0 skips dot)

    for (int s = 0; s < Ss; ++s) {
        const int wr = s & 1, rd = wr ^ 1;
        const int pos = dir ? (Ss - 1 - s) : s;

        if (s > 0) {
            // ---- acquire h(s-1) for this thread's k-slice ----
            unsigned int hA[16], hB[16];
            if (p == us) {
                const uint4* ha = (const uint4*)&h16loc[(0 * 2 + rd) * 32 + half * 16];
                const uint4* hb = (const uint4*)&h16loc[(1 * 2 + rd) * 32 + half * 16];
                #pragma unroll
                for (int i = 0; i < 4; ++i) {
                    uint4 qa = ha[i], qb = hb[i];
                    hA[i*4] = qa.x; hA[i*4+1] = qa.y; hA[i*4+2] = qa.z; hA[i*4+3] = qa.w;
                    hB[i*4] = qb.x; hB[i*4+1] = qb.y; hB[i*4+2] = qb.z; hB[i*4+3] = qb.w;
                }
            } else {
                const int fA = fl_base + p * 2 + 0, fB = fl_base + p * 2 + 1;
                while (true) {
                    int a = __hip_atomic_load(&flags[fA], __ATOMIC_ACQUIRE,
                                              __HIP_MEMORY_SCOPE_AGENT);
                    int bb = __hip_atomic_load(&flags[fB], __ATOMIC_ACQUIRE,
                                               __HIP_MEMORY_SCOPE_AGENT);
                    if (a >= s && bb >= s) break;
                    if (--budget < 0) break;
                }
                const uint4* ga = (const uint4*)&hgT[(p * 2 + rd) * 64 + 0 * 32 + half * 16];
                const uint4* gb = (const uint4*)&hgT[(p * 2 + rd) * 64 + 1 * 32 + half * 16];
                #pragma unroll
                for (int i = 0; i < 4; ++i) {
                    uint4 qa = ga[i], qb = gb[i];
                    hA[i*4] = qa.x; hA[i*4+1] = qa.y; hA[i*4+2] = qa.z; hA[i*4+3] = qa.w;
                    hB[i*4] = qb.x; hB[i*4+1] = qb.y; hB[i*4+2] = qb.z; hB[i*4+3] = qb.w;
                }
            }
            // ---- dot: 16 k-pairs x 4 gates x 2 batches, weights from LDS ----
            float4 aA = make_float4(0.f,0.f,0.f,0.f), aB = make_float4(0.f,0.f,0.f,0.f);
            const uint4* wp = &LW4[kp0 * 64 + u_loc];
            #pragma unroll
            for (int i = 0; i < 16; ++i) {
                const uint4 w = wp[i * 64];
                aA.x = fdot2u(hA[i], w.x, aA.x);
                aA.y = fdot2u(hA[i], w.y, aA.y);
                aA.z = fdot2u(hA[i], w.z, aA.z);
                aA.w = fdot2u(hA[i], w.w, aA.w);
                aB.x = fdot2u(hB[i], w.x, aB.x);
                aB.y = fdot2u(hB[i], w.y, aB.y);
                aB.z = fdot2u(hB[i], w.z, aB.z);
                aB.w = fdot2u(hB[i], w.w, aB.w);
            }
            // ---- 8-way reduce within 8-lane group ----
            #pragma unroll
            for (int off = 4; off > 0; off >>= 1) {
                aA.x += __shfl_down(aA.x, off); aA.y += __shfl_down(aA.y, off);
                aA.z += __shfl_down(aA.z, off); aA.w += __shfl_down(aA.w, off);
                aB.x += __shfl_down(aB.x, off); aB.y += __shfl_down(aB.y, off);
                aB.z += __shfl_down(aB.z, off); aB.w += __shfl_down(aB.w, off);
            }
            if (kq2 == 0) {
                *(float4*)&part[(0 * 64 + u_loc) * 4] = aA;
                *(float4*)&part[(1 * 64 + u_loc) * 4] = aB;
            }
        }
        __syncthreads();   // b1: part[] ready

        if (wave < 2) {
            float4 g4 = ep;
            if (s > 0) {
                const float4 pp = *(const float4*)&part[(bat * 64 + lane) * 4];
                g4.x += pp.x; g4.y += pp.y; g4.z += pp.z; g4.w += pp.w;
            }
            c = sigm(g4.y) * c + sigm(g4.x) * tanhf(g4.z);
            const float h = sigm(g4.w) * tanhf(c);
            // fused emission: partial over this quarter, 4 tags
            float4 em = make_float4(h * wl.x, h * wl.y, h * wl.z, h * wl.w);
            #pragma unroll
            for (int off = 32; off > 0; off >>= 1) {
                em.x += __shfl_down(em.x, off); em.y += __shfl_down(em.y, off);
                em.z += __shfl_down(em.z, off); em.w += __shfl_down(em.w, off);
            }
            if (lane == 0)
                *(float4*)&emisP[(((size_t)di * Ss + pos) * Bb + b) * 4] = em;
            // pack h -> f16x2, publish locally + globally
            const float hn = __shfl_down(h, 1);
            if (!(lane & 1)) {
                union { _Float16 hh[2]; unsigned int u32; } pk;
                pk.hh[0] = (_Float16)h; pk.hh[1] = (_Float16)hn;
                h16loc[(bat * 2 + wr) * 32 + (lane >> 1)] = pk.u32;
                hgT[(us * 2 + wr) * 64 + bat * 32 + (lane >> 1)] = pk.u32;
            }
            if (lane == 0)   // release waits the wave's vmem stores (wave-level vmcnt)
                __hip_atomic_store(&flags[fl_base + us * 2 + bat], s + 1,
                                   __ATOMIC_RELEASE, __HIP_MEMORY_SCOPE_AGENT);
            if (s + 1 < Ss) {   // prefetch next token's gate preactivations
                const int pn = dir ? (Ss - 2 - s) : (s + 1);
                ep = *(const float4*)(EP + (size_t)sent[pn] * 1024 + uact * 4);
            }
        }
        __syncthreads();   // b2: h16loc[wr] visible; part[] free for reuse
    }
}

// ---------------------------------------------------------------------------
// merge 8 emission partials -> emis[s][b][4]
// ---------------------------------------------------------------------------
__global__ __launch_bounds__(256) void emis_merge_kernel(const float* __restrict__ emisP,
                                                         float* __restrict__ emis)
{
    const int i = blockIdx.x * 256 + threadIdx.x;   // < 131072
    float v = 0.f;
    #pragma unroll
    for (int d = 0; d < 8; ++d) v += emisP[(size_t)d * (Ss * Bb * 4) + i];
    emis[i] = v;
}

// ---------------------------------------------------------------------------
// Fused CRF + Viterbi tail. grid 8 x 64 threads.
// ---------------------------------------------------------------------------
__global__ __launch_bounds__(64) void tail_kernel(
    const float* __restrict__ emis,
    const float* __restrict__ blin, const float* __restrict__ start_t,
    const float* __restrict__ end_t, const float* __restrict__ trans,
    const int* __restrict__ tags, float* __restrict__ out_tags,
    float* __restrict__ out_loss)
{
    const int blk = blockIdx.x;
    const int t = threadIdx.x;
    const int b_loc = t >> 2, j = t & 3;
    const int base = t & ~3;

    if (blk < 4) {
        __shared__ unsigned char bp_sh[16][513][4];
        __shared__ unsigned char tag_sh[16][520];
        const int b = blk * 16 + b_loc;
        const float trj0 = trans[0*4+j], trj1 = trans[1*4+j],
                    trj2 = trans[2*4+j], trj3 = trans[3*4+j];
        const float blj = blin[j];
        float score = start_t[j] + emis[(size_t)b*4 + j] + blj;
        for (int s = 1; s < Ss; ++s) {
            const float e = emis[((size_t)s*Bb + b)*4 + j] + blj;
            const float s0 = __shfl(score, base+0), s1 = __shfl(score, base+1),
                        s2 = __shfl(score, base+2), s3 = __shfl(score, base+3);
            float best = s0 + trj0; int bi = 0;
            float v = s1 + trj1; if (v > best) { best = v; bi = 1; }
            v = s2 + trj2; if (v > best) { best = v; bi = 2; }
            v = s3 + trj3; if (v > best) { best = v; bi = 3; }
            score = best + e;
            bp_sh[b_loc][s][j] = (unsigned char)bi;
        }
        const float fv = score + end_t[j];
        const float f0 = __shfl(fv, base+0), f1 = __shfl(fv, base+1),
                    f2 = __shfl(fv, base+2), f3 = __shfl(fv, base+3);
        __syncthreads();
        if (j == 0) {   // backtrack (first-occurrence argmax, like jnp)
            float best = f0; int tag = 0;
            if (f1 > best) { best = f1; tag = 1; }
            if (f2 > best) { best = f2; tag = 2; }
            if (f3 > best) { best = f3; tag = 3; }
            tag_sh[b_loc][Ss-1] = (unsigned char)tag;
            for (int s = Ss - 1; s >= 1; --s) {
                tag = bp_sh[b_loc][s][tag];
                tag_sh[b_loc][s-1] = (unsigned char)tag;
            }
        }
        __syncthreads();
        for (int idx = t; idx < 16 * Ss; idx += 64) {
            const int bl = idx >> 9, s = idx & (Ss - 1);
            out_tags[(size_t)(blk*16 + bl) * Ss + s] = (float)tag_sh[bl][s];
        }
    } else {
        const int b = (blk - 4) * 16 + b_loc;
        const float trj0 = trans[0*4+j], trj1 = trans[1*4+j],
                    trj2 = trans[2*4+j], trj3 = trans[3*4+j];
        const float blj = blin[j];
        float alpha = start_t[j] + emis[(size_t)b*4 + j] + blj;
        for (int s = 1; s < Ss; ++s) {
            const float e = emis[((size_t)s*Bb + b)*4 + j] + blj;
            const float a0 = __shfl(alpha, base+0), a1 = __shfl(alpha, base+1),
                        a2 = __shfl(alpha, base+2), a3 = __shfl(alpha, base+3);
            const float x0 = a0 + trj0, x1 = a1 + trj1, x2 = a2 + trj2, x3 = a3 + trj3;
            const float m = fmaxf(fmaxf(x0, x1), fmaxf(x2, x3));
            alpha = m + logf(expf(x0-m) + expf(x1-m) + expf(x2-m) + expf(x3-m)) + e;
        }
        const float dv = alpha + end_t[j];
        const float d0 = __shfl(dv, base+0), d1 = __shfl(dv, base+1),
                    d2 = __shfl(dv, base+2), d3 = __shfl(dv, base+3);
        const float dm = fmaxf(fmaxf(d0, d1), fmaxf(d2, d3));
        const float denom = dm + logf(expf(d0-dm) + expf(d1-dm) + expf(d2-dm) + expf(d3-dm));

        const int lo = j * 128, hi = lo + 128;
        float num = 0.f;
        int tprev = (lo > 0) ? tags[(size_t)b*Ss + lo - 1] : 0;
        if (j == 0) num += start_t[tags[(size_t)b*Ss]];
        if (j == 3) num += end_t[tags[(size_t)b*Ss + Ss - 1]];
        for (int s = lo; s < hi; ++s) {
            const int tg = tags[(size_t)b*Ss + s];
            num += emis[((size_t)s*Bb + b)*4 + tg] + blin[tg];
            if (s > 0) num += trans[tprev*4 + tg];
            tprev = tg;
        }
        num += __shfl_xor(num, 1);
        num += __shfl_xor(num, 2);
        float lb = (j == 0) ? (denom - num) : 0.f;
        #pragma unroll
        for (int off = 32; off > 0; off >>= 1) lb += __shfl_down(lb, off);
        if (t == 0) atomicAdd(out_loss, lb);
    }
}

// ---------------------------------------------------------------------------
extern "C" void kernel_launch(void* const* d_in, const int* in_sizes, int n_in,
                              void* d_out, int out_size, void* d_ws, size_t ws_size,
                              hipStream_t stream)
{
    const int*   sentence = (const int*)d_in[0];
    const int*   tags     = (const int*)d_in[1];
    const float* emb      = (const float*)d_in[3];
    const float* Wih_f    = (const float*)d_in[4];
    const float* Whh_f    = (const float*)d_in[5];
    const float* b_f      = (const float*)d_in[6];
    const float* Wih_b    = (const float*)d_in[7];
    const float* Whh_b    = (const float*)d_in[8];
    const float* b_b      = (const float*)d_in[9];
    const float* Wlin     = (const float*)d_in[10];
    const float* blin     = (const float*)d_in[11];
    const float* start_t  = (const float*)d_in[12];
    const float* end_t    = (const float*)d_in[13];
    const float* trans    = (const float*)d_in[14];

    // workspace layout (floats)
    float*        embproj = (float*)d_ws;                      // 16,384,000
    float*        WihP    = embproj + 2 * EPROJ_PER_DIR;       // 524,288 (reused)
    unsigned int* W16p    = (unsigned int*)(WihP + 2 * WMAT_PER_DIR);  // 262,144 u32
    float*        bP      = (float*)(W16p + 262144);           // 2048
    float*        WlinQ   = bP + 2048;                         // 2048
    float*        emisP   = WlinQ + 2048;                      // 8*512*64*4 = 1,048,576
    float*        emis    = emisP + 8 * Ss * Bb * 4;           // 131,072

    // WihP region dead after the GEMM -> flags + h exchange
    int*          flags  = (int*)WihP;                         // 512 ints
    unsigned int* hg     = (unsigned int*)(WihP + 1024);       // 64*4*2*2*32 = 32768 u32

    prep_kernel<<<2048, 256, 0, stream>>>(Wih_f, Whh_f, b_f, Wih_b, Whh_b, b_b, Wlin,
                                          WihP, W16p, bP, WlinQ);
    dim3 gg(Vv / BM, 1024 / BN, 2);
    embproj_gemm<<<gg, 256, 0, stream>>>(emb, WihP, bP, embproj);

    hipMemsetAsync(flags, 0, 512 * sizeof(int), stream);

    const int* k_sent = sentence;
    const float* k_ep = embproj;
    const unsigned int* k_w = W16p;
    const float* k_wlin = WlinQ;
    unsigned int* k_hg = hg;
    int* k_fl = flags;
    float* k_em = emisP;
    void* args[] = { (void*)&k_sent, (void*)&k_ep, (void*)&k_w, (void*)&k_wlin,
                     (void*)&k_hg, (void*)&k_fl, (void*)&k_em };
    hipLaunchCooperativeKernel((const void*)lstm_lds_kernel, dim3(256), dim3(512),
                               args, 133632, stream);

    emis_merge_kernel<<<512, 256, 0, stream>>>(emisP, emis);

    float* out = (float*)d_out;
    float* out_loss = out + Bb * Ss;
    hipMemsetAsync(out_loss, 0, sizeof(float), stream);
    tail_kernel<<<8, 64, 0, stream>>>(emis, blin, start_t, end_t, trans,
                                      tags, out, out_loss);
}

// Round 7
// 7433.839 us; speedup vs baseline: 3.8871x; 3.8871x over previous
//
#include <hip/hip_runtime.h>
#include <math.h>

// Problem constants
#define Vv 8000
#define Ee 256
#define Hh 256
#define Tt 4
#define Bb 64
#define Ss 512

#define EPROJ_PER_DIR (Vv * 1024)   // 8,192,000 floats per direction
#define WMAT_PER_DIR  (Ee * 1024)   // 262,144 floats per direction

__device__ __forceinline__ float sigm(float x) { return 1.f / (1.f + expf(-x)); }

typedef _Float16 half2v __attribute__((ext_vector_type(2)));

__device__ __forceinline__ float fdot2u(unsigned int a, unsigned int b, float c) {
    half2v ha = __builtin_bit_cast(half2v, a);
    half2v hb = __builtin_bit_cast(half2v, b);
#if __has_builtin(__builtin_amdgcn_fdot2)
    return __builtin_amdgcn_fdot2(ha, hb, c, false);
#else
    return c + (float)ha[0] * (float)hb[0] + (float)ha[1] * (float)hb[1];
#endif
}

// ---------------------------------------------------------------------------
// prep: repack weights.
//   WihP [dir][e][j']  j' = u*4+g <-> gate-row g*256+u     (GEMM B-matrix)
//   W16p [dir][us][kp][u_loc][g] u32 = f16x2 over k-pairs  (recurrent, LDS image)
//   bP   [dir][j']
//   WlinQ[dir][u][t] float4/u = Wlin[t][dir*256+u]         (emission)
// ---------------------------------------------------------------------------
__global__ void prep_kernel(const float* __restrict__ Wih_f, const float* __restrict__ Whh_f,
                            const float* __restrict__ b_f,
                            const float* __restrict__ Wih_b, const float* __restrict__ Whh_b,
                            const float* __restrict__ b_b,
                            const float* __restrict__ Wlin,
                            float* __restrict__ WihP, unsigned int* __restrict__ W16p,
                            float* __restrict__ bP, float* __restrict__ WlinQ)
{
    int tid = blockIdx.x * blockDim.x + threadIdx.x;   // [0, 2*262144)
    int dir = tid >> 18;
    int r   = tid & 262143;
    int k   = r >> 10;        // 0..255
    int jp  = r & 1023;       // j'
    int u   = jp >> 2;
    int g   = jp & 3;
    int row = g * 256 + u;    // original gate row
    const float* Wih = dir ? Wih_b : Wih_f;
    const float* Whh = dir ? Whh_b : Whh_f;
    const float* bv  = dir ? b_b   : b_f;
    WihP[dir * WMAT_PER_DIR + k * 1024 + jp] = Wih[row * 256 + k];
    if (!(k & 1)) {
        int kp = k >> 1;                 // 0..127
        int us = u >> 6, u_loc = u & 63;
        union { _Float16 h[2]; unsigned int u32; } pk;
        pk.h[0] = (_Float16)Whh[row * 256 + k];
        pk.h[1] = (_Float16)Whh[row * 256 + k + 1];
        W16p[(((dir * 4 + us) * 128 + kp) * 64 + u_loc) * 4 + g] = pk.u32;
    }
    if (r < 1024) {
        bP[dir * 1024 + jp] = bv[row];
        int uu = r >> 2, tt = r & 3;
        WlinQ[(dir * 256 + uu) * 4 + tt] = Wlin[tt * (2 * Hh) + dir * 256 + uu];
    }
}

// ---------------------------------------------------------------------------
// embproj GEMM: embproj[dir][v][j'] = sum_e emb[v][e]*WihP[dir][e][j'] + bP[dir][j']
// ---------------------------------------------------------------------------
#define BM 64
#define BN 128
#define BK 16
__global__ __launch_bounds__(256) void embproj_gemm(const float* __restrict__ emb,
                                                    const float* __restrict__ WihP,
                                                    const float* __restrict__ bP,
                                                    float* __restrict__ embproj)
{
    int dir = blockIdx.z;
    const float* Bmat = WihP + dir * WMAT_PER_DIR;
    float* C = embproj + (size_t)dir * EPROJ_PER_DIR;
    int m0 = blockIdx.x * BM;
    int n0 = blockIdx.y * BN;

    __shared__ float As[BK][BM];
    __shared__ float Bs[BK][BN];

    int t = threadIdx.x;
    int tm = (t & 15) * 4;
    int tn = (t >> 4) * 8;
    float acc[4][8];
    #pragma unroll
    for (int i = 0; i < 4; ++i)
        #pragma unroll
        for (int j = 0; j < 8; ++j) acc[i][j] = 0.f;

    for (int k0 = 0; k0 < Ee; k0 += BK) {
        {   // A tile 64x16
            int row = t >> 2, seg = t & 3;
            float4 a4 = *(const float4*)(&emb[(size_t)(m0 + row) * Ee + k0 + seg * 4]);
            As[seg * 4 + 0][row] = a4.x;
            As[seg * 4 + 1][row] = a4.y;
            As[seg * 4 + 2][row] = a4.z;
            As[seg * 4 + 3][row] = a4.w;
        }
        {   // B tile 16x128
            int kk = t >> 4, nn = (t & 15) * 8;
            float4 b0 = *(const float4*)(&Bmat[(size_t)(k0 + kk) * 1024 + n0 + nn]);
            float4 b1 = *(const float4*)(&Bmat[(size_t)(k0 + kk) * 1024 + n0 + nn + 4]);
            *(float4*)&Bs[kk][nn]     = b0;
            *(float4*)&Bs[kk][nn + 4] = b1;
        }
        __syncthreads();
        #pragma unroll
        for (int k = 0; k < BK; ++k) {
            float4 a  = *(const float4*)&As[k][tm];
            float4 b0 = *(const float4*)&Bs[k][tn];
            float4 b1 = *(const float4*)&Bs[k][tn + 4];
            float av[4] = {a.x, a.y, a.z, a.w};
            float bv[8] = {b0.x, b0.y, b0.z, b0.w, b1.x, b1.y, b1.z, b1.w};
            #pragma unroll
            for (int i = 0; i < 4; ++i)
                #pragma unroll
                for (int j = 0; j < 8; ++j)
                    acc[i][j] += av[i] * bv[j];
        }
        __syncthreads();
    }
    #pragma unroll
    for (int i = 0; i < 4; ++i) {
        int m = m0 + tm + i;
        #pragma unroll
        for (int j = 0; j < 8; j += 4) {
            float4 o;
            o.x = acc[i][j + 0] + bP[dir * 1024 + n0 + tn + j + 0];
            o.y = acc[i][j + 1] + bP[dir * 1024 + n0 + tn + j + 1];
            o.z = acc[i][j + 2] + bP[dir * 1024 + n0 + tn + j + 2];
            o.w = acc[i][j + 3] + bP[dir * 1024 + n0 + tn + j + 3];
            *(float4*)&C[(size_t)m * 1024 + n0 + tn + j] = o;
        }
    }
}

// ---------------------------------------------------------------------------
// LSTM recurrence, LDS-resident f16 weights, XOR-swizzled layout.
// 64 teams = dir(2) x batch-pair(32); 4 WGs/team (us = quarter of 64 units);
// grid 256 x 512, 1 WG/CU, cooperative. bx = us*64+team -> bx%8 = team%8 so
// team members co-locate on one XCD under round-robin dispatch.
//   thread: u_loc = tid>>3 (unit in quarter), kq2 = tid&7 (32-k slice).
//   Weight LDS swizzle (G4): LW4[idx ^ ((idx>>10)&7)] -- XOR varies with the
//   k-slice so the 8 lanes of a lane-group hit 8 distinct bank quads (R6 had
//   them all on one: 2e8 conflict cycles).
//   h: full 256 units f16x2 in LDS, double-buffered by parity. Act waves 0/1
//   write own quarter (LDS + 128B global) + per-(quarter,batch) release flag.
//   ONLY wave 7 imports the 3 peer quarters: 6 lanes poll 6 flags (acquire,
//   s_sleep backoff; intra-wave divergence stalls the whole wave until done),
//   then 64 lanes load 192 u32 (relaxed agent atomics, L1-bypassing) -> LDS.
//   2 barriers/step. R6's 100K concurrent pollers -> 1.5K.
// ---------------------------------------------------------------------------
__global__ __launch_bounds__(512) void lstm_lds2_kernel(
    const int* __restrict__ sentence,
    const float* __restrict__ embproj,
    const unsigned int* __restrict__ W16p,
    const float* __restrict__ WlinQ,
    unsigned int* __restrict__ hg,
    int* __restrict__ flags,
    float* __restrict__ emisP)
{
    extern __shared__ char smem[];
    uint4*        LW4  = (uint4*)smem;                        // 128 KB swizzled weights
    unsigned int* h16  = (unsigned int*)(smem + 131072);      // [bat][par][128] u32
    float*        part = (float*)(smem + 131072 + 2048);      // [bat][64][4] f32

    const int bx   = blockIdx.x;
    const int us   = bx >> 6;          // 0..3
    const int team = bx & 63;
    const int dir  = team >> 5;
    const int bg   = team & 31;
    const int b0   = bg * 2;
    const int tid  = threadIdx.x;
    const int u_loc = tid >> 3;        // 0..63
    const int kq2   = tid & 7;         // 0..7
    const int wave  = tid >> 6;
    const int lane  = tid & 63;

    // ---- stage weights into LDS, swizzled ----
    {
        const uint4* Wsrc = (const uint4*)(W16p + ((size_t)(dir * 4 + us) << 15));
        #pragma unroll
        for (int i = 0; i < 16; ++i) {
            const int idx = i * 512 + tid;
            LW4[idx ^ ((idx >> 10) & 7)] = Wsrc[idx];
        }
    }
    if (tid < 512) h16[tid] = 0u;      // h(-1) = 0 (both parities; par1 is s=0's rd)

    const float* EP = embproj + (size_t)dir * EPROJ_PER_DIR;
    const int fl_base = team * 8;
    unsigned int* hgT = hg + (size_t)team * 512;   // [q][par][bat][32] u32

    // act-wave persistent state (waves 0/1)
    const int bat = wave;              // meaningful for wave<2
    const int b = b0 + (wave < 2 ? bat : 0);
    const int* sent = sentence + (size_t)b * Ss;
    float c = 0.f;
    float4 wl = make_float4(0.f, 0.f, 0.f, 0.f);
    float4 ep = make_float4(0.f, 0.f, 0.f, 0.f);
    const int uact = us * 64 + lane;
    if (wave < 2) {
        wl = *(const float4*)&WlinQ[(dir * 256 + uact) * 4];
        const int pos0 = dir ? (Ss - 1) : 0;
        ep = *(const float4*)(EP + (size_t)sent[pos0] * 1024 + uact * 4);
    }
    const int di = us * 2 + dir;       // emission partial buffer index
    const int wbase = kq2 * 1024 + u_loc;   // uint4 idx of first weight (i=0)
    long budget = 200000000;           // bounded spin: wrong answer, not hang

    __syncthreads();

    for (int s = 0; s < Ss; ++s) {
        const int wr = s & 1, rd = wr ^ 1;
        const int pos = dir ? (Ss - 1 - s) : s;

        // ---- dot: 16 k-pairs x 4 gates x 2 batches; weights LDS (swizzled) ----
        {
            unsigned int hA[16], hB[16];
            #pragma unroll
            for (int r = 0; r < 4; ++r) {
                uint4 qa = *(const uint4*)&h16[(0 * 2 + rd) * 128 + kq2 * 16 + r * 4];
                uint4 qb = *(const uint4*)&h16[(1 * 2 + rd) * 128 + kq2 * 16 + r * 4];
                hA[r*4] = qa.x; hA[r*4+1] = qa.y; hA[r*4+2] = qa.z; hA[r*4+3] = qa.w;
                hB[r*4] = qb.x; hB[r*4+1] = qb.y; hB[r*4+2] = qb.z; hB[r*4+3] = qb.w;
            }
            float4 aA = make_float4(0.f,0.f,0.f,0.f), aB = make_float4(0.f,0.f,0.f,0.f);
            #pragma unroll
            for (int i = 0; i < 16; ++i) {
                const uint4 w = LW4[(wbase + i * 64) ^ kq2];
                aA.x = fdot2u(hA[i], w.x, aA.x);
                aA.y = fdot2u(hA[i], w.y, aA.y);
                aA.z = fdot2u(hA[i], w.z, aA.z);
                aA.w = fdot2u(hA[i], w.w, aA.w);
                aB.x = fdot2u(hB[i], w.x, aB.x);
                aB.y = fdot2u(hB[i], w.y, aB.y);
                aB.z = fdot2u(hB[i], w.z, aB.z);
                aB.w = fdot2u(hB[i], w.w, aB.w);
            }
            #pragma unroll
            for (int off = 4; off > 0; off >>= 1) {
                aA.x += __shfl_down(aA.x, off); aA.y += __shfl_down(aA.y, off);
                aA.z += __shfl_down(aA.z, off); aA.w += __shfl_down(aA.w, off);
                aB.x += __shfl_down(aB.x, off); aB.y += __shfl_down(aB.y, off);
                aB.z += __shfl_down(aB.z, off); aB.w += __shfl_down(aB.w, off);
            }
            if (kq2 == 0) {
                *(float4*)&part[(0 * 64 + u_loc) * 4] = aA;
                *(float4*)&part[(1 * 64 + u_loc) * 4] = aB;
            }
        }
        __syncthreads();   // b1: part[] ready

        if (wave < 2) {
            // ---- activation + fused emission + h publish ----
            const float4 pp = *(const float4*)&part[(bat * 64 + lane) * 4];
            const float gi = pp.x + ep.x, gf = pp.y + ep.y,
                        gg = pp.z + ep.z, go = pp.w + ep.w;
            c = sigm(gf) * c + sigm(gi) * tanhf(gg);
            const float h = sigm(go) * tanhf(c);
            float4 em = make_float4(h * wl.x, h * wl.y, h * wl.z, h * wl.w);
            #pragma unroll
            for (int off = 32; off > 0; off >>= 1) {
                em.x += __shfl_down(em.x, off); em.y += __shfl_down(em.y, off);
                em.z += __shfl_down(em.z, off); em.w += __shfl_down(em.w, off);
            }
            if (lane == 0)
                *(float4*)&emisP[(((size_t)di * Ss + pos) * Bb + b) * 4] = em;
            const float hn = __shfl_down(h, 1);
            if (!(lane & 1)) {
                union { _Float16 hh[2]; unsigned int u32; } pk;
                pk.hh[0] = (_Float16)h; pk.hh[1] = (_Float16)hn;
                const int slot = us * 32 + (lane >> 1);
                h16[(bat * 2 + wr) * 128 + slot] = pk.u32;
                hgT[((us * 2 + wr) * 2 + bat) * 32 + (lane >> 1)] = pk.u32;
            }
            if (lane == 0)   // release waits this wave's vmem stores
                __hip_atomic_store(&flags[fl_base + us * 2 + bat], s + 1,
                                   __ATOMIC_RELEASE, __HIP_MEMORY_SCOPE_AGENT);
            if (s + 1 < Ss) {
                const int pn = dir ? (Ss - 2 - s) : (s + 1);
                ep = *(const float4*)(EP + (size_t)sent[pn] * 1024 + uact * 4);
            }
        } else if (wave == 7 && s + 1 < Ss) {
            // ---- import 3 peer quarters of h(s) ----
            if (lane < 6) {
                const int pi = lane >> 1;
                const int q  = pi + (pi >= us);
                const int* fp = &flags[fl_base + q * 2 + (lane & 1)];
                while (__hip_atomic_load(fp, __ATOMIC_ACQUIRE,
                                         __HIP_MEMORY_SCOPE_AGENT) < s + 1) {
                    __builtin_amdgcn_s_sleep(2);
                    if (--budget < 0) break;
                }
            }
            const int bt = lane >> 5, idx32 = lane & 31;
            #pragma unroll
            for (int pi = 0; pi < 3; ++pi) {
                const int q = pi + (pi >= us);
                const unsigned int v = __hip_atomic_load(
                    &hgT[((q * 2 + wr) * 2 + bt) * 32 + idx32],
                    __ATOMIC_RELAXED, __HIP_MEMORY_SCOPE_AGENT);
                h16[(bt * 2 + wr) * 128 + q * 32 + idx32] = v;
            }
        }
        __syncthreads();   // b2: h16[wr] complete
    }
}

// ---------------------------------------------------------------------------
// merge 8 emission partials -> emis[s][b][4]
// ---------------------------------------------------------------------------
__global__ __launch_bounds__(256) void emis_merge_kernel(const float* __restrict__ emisP,
                                                         float* __restrict__ emis)
{
    const int i = blockIdx.x * 256 + threadIdx.x;   // < 131072
    float v = 0.f;
    #pragma unroll
    for (int d = 0; d < 8; ++d) v += emisP[(size_t)d * (Ss * Bb * 4) + i];
    emis[i] = v;
}

// ---------------------------------------------------------------------------
// Fused CRF + Viterbi tail. grid 8 x 64 threads.
// ---------------------------------------------------------------------------
__global__ __launch_bounds__(64) void tail_kernel(
    const float* __restrict__ emis,
    const float* __restrict__ blin, const float* __restrict__ start_t,
    const float* __restrict__ end_t, const float* __restrict__ trans,
    const int* __restrict__ tags, float* __restrict__ out_tags,
    float* __restrict__ out_loss)
{
    const int blk = blockIdx.x;
    const int t = threadIdx.x;
    const int b_loc = t >> 2, j = t & 3;
    const int base = t & ~3;

    if (blk < 4) {
        __shared__ unsigned char bp_sh[16][513][4];
        __shared__ unsigned char tag_sh[16][520];
        const int b = blk * 16 + b_loc;
        const float trj0 = trans[0*4+j], trj1 = trans[1*4+j],
                    trj2 = trans[2*4+j], trj3 = trans[3*4+j];
        const float blj = blin[j];
        float score = start_t[j] + emis[(size_t)b*4 + j] + blj;
        for (int s = 1; s < Ss; ++s) {
            const float e = emis[((size_t)s*Bb + b)*4 + j] + blj;
            const float s0 = __shfl(score, base+0), s1 = __shfl(score, base+1),
                        s2 = __shfl(score, base+2), s3 = __shfl(score, base+3);
            float best = s0 + trj0; int bi = 0;
            float v = s1 + trj1; if (v > best) { best = v; bi = 1; }
            v = s2 + trj2; if (v > best) { best = v; bi = 2; }
            v = s3 + trj3; if (v > best) { best = v; bi = 3; }
            score = best + e;
            bp_sh[b_loc][s][j] = (unsigned char)bi;
        }
        const float fv = score + end_t[j];
        const float f0 = __shfl(fv, base+0), f1 = __shfl(fv, base+1),
                    f2 = __shfl(fv, base+2), f3 = __shfl(fv, base+3);
        __syncthreads();
        if (j == 0) {   // backtrack (first-occurrence argmax, like jnp)
            float best = f0; int tag = 0;
            if (f1 > best) { best = f1; tag = 1; }
            if (f2 > best) { best = f2; tag = 2; }
            if (f3 > best) { best = f3; tag = 3; }
            tag_sh[b_loc][Ss-1] = (unsigned char)tag;
            for (int s = Ss - 1; s >= 1; --s) {
                tag = bp_sh[b_loc][s][tag];
                tag_sh[b_loc][s-1] = (unsigned char)tag;
            }
        }
        __syncthreads();
        for (int idx = t; idx < 16 * Ss; idx += 64) {
            const int bl = idx >> 9, s = idx & (Ss - 1);
            out_tags[(size_t)(blk*16 + bl) * Ss + s] = (float)tag_sh[bl][s];
        }
    } else {
        const int b = (blk - 4) * 16 + b_loc;
        const float trj0 = trans[0*4+j], trj1 = trans[1*4+j],
                    trj2 = trans[2*4+j], trj3 = trans[3*4+j];
        const float blj = blin[j];
        float alpha = start_t[j] + emis[(size_t)b*4 + j] + blj;
        for (int s = 1; s < Ss; ++s) {
            const float e = emis[((size_t)s*Bb + b)*4 + j] + blj;
            const float a0 = __shfl(alpha, base+0), a1 = __shfl(alpha, base+1),
                        a2 = __shfl(alpha, base+2), a3 = __shfl(alpha, base+3);
            const float x0 = a0 + trj0, x1 = a1 + trj1, x2 = a2 + trj2, x3 = a3 + trj3;
            const float m = fmaxf(fmaxf(x0, x1), fmaxf(x2, x3));
            alpha = m + logf(expf(x0-m) + expf(x1-m) + expf(x2-m) + expf(x3-m)) + e;
        }
        const float dv = alpha + end_t[j];
        const float d0 = __shfl(dv, base+0), d1 = __shfl(dv, base+1),
                    d2 = __shfl(dv, base+2), d3 = __shfl(dv, base+3);
        const float dm = fmaxf(fmaxf(d0, d1), fmaxf(d2, d3));
        const float denom = dm + logf(expf(d0-dm) + expf(d1-dm) + expf(d2-dm) + expf(d3-dm));

        const int lo = j * 128, hi = lo + 128;
        float num = 0.f;
        int tprev = (lo > 0) ? tags[(size_t)b*Ss + lo - 1] : 0;
        if (j == 0) num += start_t[tags[(size_t)b*Ss]];
        if (j == 3) num += end_t[tags[(size_t)b*Ss + Ss - 1]];
        for (int s = lo; s < hi; ++s) {
            const int tg = tags[(size_t)b*Ss + s];
            num += emis[((size_t)s*Bb + b)*4 + tg] + blin[tg];
            if (s > 0) num += trans[tprev*4 + tg];
            tprev = tg;
        }
        num += __shfl_xor(num, 1);
        num += __shfl_xor(num, 2);
        float lb = (j == 0) ? (denom - num) : 0.f;
        #pragma unroll
        for (int off = 32; off > 0; off >>= 1) lb += __shfl_down(lb, off);
        if (t == 0) atomicAdd(out_loss, lb);
    }
}

// ---------------------------------------------------------------------------
extern "C" void kernel_launch(void* const* d_in, const int* in_sizes, int n_in,
                              void* d_out, int out_size, void* d_ws, size_t ws_size,
                              hipStream_t stream)
{
    const int*   sentence = (const int*)d_in[0];
    const int*   tags     = (const int*)d_in[1];
    const float* emb      = (const float*)d_in[3];
    const float* Wih_f    = (const float*)d_in[4];
    const float* Whh_f    = (const float*)d_in[5];
    const float* b_f      = (const float*)d_in[6];
    const float* Wih_b    = (const float*)d_in[7];
    const float* Whh_b    = (const float*)d_in[8];
    const float* b_b      = (const float*)d_in[9];
    const float* Wlin     = (const float*)d_in[10];
    const float* blin     = (const float*)d_in[11];
    const float* start_t  = (const float*)d_in[12];
    const float* end_t    = (const float*)d_in[13];
    const float* trans    = (const float*)d_in[14];

    // workspace layout (floats)
    float*        embproj = (float*)d_ws;                      // 16,384,000
    float*        WihP    = embproj + 2 * EPROJ_PER_DIR;       // 524,288 (reused)
    unsigned int* W16p    = (unsigned int*)(WihP + 2 * WMAT_PER_DIR);  // 262,144 u32
    float*        bP      = (float*)(W16p + 262144);           // 2048
    float*        WlinQ   = bP + 2048;                         // 2048
    float*        emisP   = WlinQ + 2048;                      // 8*512*64*4
    float*        emis    = emisP + 8 * Ss * Bb * 4;           // 131,072

    // WihP region dead after the GEMM -> flags + h exchange
    int*          flags  = (int*)WihP;                         // 512 ints
    unsigned int* hg     = (unsigned int*)(WihP + 1024);       // 64*512 u32

    prep_kernel<<<2048, 256, 0, stream>>>(Wih_f, Whh_f, b_f, Wih_b, Whh_b, b_b, Wlin,
                                          WihP, W16p, bP, WlinQ);
    dim3 gg(Vv / BM, 1024 / BN, 2);
    embproj_gemm<<<gg, 256, 0, stream>>>(emb, WihP, bP, embproj);

    hipMemsetAsync(flags, 0, 512 * sizeof(int), stream);

    const int* k_sent = sentence;
    const float* k_ep = embproj;
    const unsigned int* k_w = W16p;
    const float* k_wlin = WlinQ;
    unsigned int* k_hg = hg;
    int* k_fl = flags;
    float* k_em = emisP;
    void* args[] = { (void*)&k_sent, (void*)&k_ep, (void*)&k_w, (void*)&k_wlin,
                     (void*)&k_hg, (void*)&k_fl, (void*)&k_em };
    hipLaunchCooperativeKernel((const void*)lstm_lds2_kernel, dim3(256), dim3(512),
                               args, 131072 + 2048 + 2048, stream);

    emis_merge_kernel<<<512, 256, 0, stream>>>(emisP, emis);

    float* out = (float*)d_out;
    float* out_loss = out + Bb * Ss;
    hipMemsetAsync(out_loss, 0, sizeof(float), stream);
    tail_kernel<<<8, 64, 0, stream>>>(emis, blin, start_t, end_t, trans,
                                      tags, out, out_loss);
}

// Round 8
// 2033.260 us; speedup vs baseline: 14.2116x; 3.6561x over previous
//
#include <hip/hip_runtime.h>
#include <math.h>

// Problem constants
#define Vv 8000
#define Ee 256
#define Hh 256
#define Tt 4
#define Bb 64
#define Ss 512

#define EPROJ_PER_DIR (Vv * 1024)   // 8,192,000 floats per direction
#define WMAT_PER_DIR  (Ee * 1024)   // 262,144 floats per direction

__device__ __forceinline__ float sigm(float x) { return 1.f / (1.f + expf(-x)); }

typedef _Float16 half2v __attribute__((ext_vector_type(2)));

__device__ __forceinline__ float fdot2u(unsigned int a, unsigned int b, float c) {
    half2v ha = __builtin_bit_cast(half2v, a);
    half2v hb = __builtin_bit_cast(half2v, b);
#if __has_builtin(__builtin_amdgcn_fdot2)
    return __builtin_amdgcn_fdot2(ha, hb, c, false);
#else
    return c + (float)ha[0] * (float)hb[0] + (float)ha[1] * (float)hb[1];
#endif
}

// ---------------------------------------------------------------------------
// prep: repack weights.
//   WihP [dir][e][j']  j' = u*4+g <-> gate-row g*256+u     (GEMM B-matrix)
//   W16p [dir][us][kp][u_loc][g] u32 = f16x2 over k-pairs  (recurrent, LDS image)
//   bP   [dir][j']
//   WlinQ[dir][u][t] float4/u = Wlin[t][dir*256+u]         (emission)
// ---------------------------------------------------------------------------
__global__ void prep_kernel(const float* __restrict__ Wih_f, const float* __restrict__ Whh_f,
                            const float* __restrict__ b_f,
                            const float* __restrict__ Wih_b, const float* __restrict__ Whh_b,
                            const float* __restrict__ b_b,
                            const float* __restrict__ Wlin,
                            float* __restrict__ WihP, unsigned int* __restrict__ W16p,
                            float* __restrict__ bP, float* __restrict__ WlinQ)
{
    int tid = blockIdx.x * blockDim.x + threadIdx.x;   // [0, 2*262144)
    int dir = tid >> 18;
    int r   = tid & 262143;
    int k   = r >> 10;        // 0..255
    int jp  = r & 1023;       // j'
    int u   = jp >> 2;
    int g   = jp & 3;
    int row = g * 256 + u;    // original gate row
    const float* Wih = dir ? Wih_b : Wih_f;
    const float* Whh = dir ? Whh_b : Whh_f;
    const float* bv  = dir ? b_b   : b_f;
    WihP[dir * WMAT_PER_DIR + k * 1024 + jp] = Wih[row * 256 + k];
    if (!(k & 1)) {
        int kp = k >> 1;                 // 0..127
        int us = u >> 6, u_loc = u & 63;
        union { _Float16 h[2]; unsigned int u32; } pk;
        pk.h[0] = (_Float16)Whh[row * 256 + k];
        pk.h[1] = (_Float16)Whh[row * 256 + k + 1];
        W16p[(((dir * 4 + us) * 128 + kp) * 64 + u_loc) * 4 + g] = pk.u32;
    }
    if (r < 1024) {
        bP[dir * 1024 + jp] = bv[row];
        int uu = r >> 2, tt = r & 3;
        WlinQ[(dir * 256 + uu) * 4 + tt] = Wlin[tt * (2 * Hh) + dir * 256 + uu];
    }
}

// ---------------------------------------------------------------------------
// embproj GEMM: embproj[dir][v][j'] = sum_e emb[v][e]*WihP[dir][e][j'] + bP[dir][j']
// ---------------------------------------------------------------------------
#define BM 64
#define BN 128
#define BK 16
__global__ __launch_bounds__(256) void embproj_gemm(const float* __restrict__ emb,
                                                    const float* __restrict__ WihP,
                                                    const float* __restrict__ bP,
                                                    float* __restrict__ embproj)
{
    int dir = blockIdx.z;
    const float* Bmat = WihP + dir * WMAT_PER_DIR;
    float* C = embproj + (size_t)dir * EPROJ_PER_DIR;
    int m0 = blockIdx.x * BM;
    int n0 = blockIdx.y * BN;

    __shared__ float As[BK][BM];
    __shared__ float Bs[BK][BN];

    int t = threadIdx.x;
    int tm = (t & 15) * 4;
    int tn = (t >> 4) * 8;
    float acc[4][8];
    #pragma unroll
    for (int i = 0; i < 4; ++i)
        #pragma unroll
        for (int j = 0; j < 8; ++j) acc[i][j] = 0.f;

    for (int k0 = 0; k0 < Ee; k0 += BK) {
        {   // A tile 64x16
            int row = t >> 2, seg = t & 3;
            float4 a4 = *(const float4*)(&emb[(size_t)(m0 + row) * Ee + k0 + seg * 4]);
            As[seg * 4 + 0][row] = a4.x;
            As[seg * 4 + 1][row] = a4.y;
            As[seg * 4 + 2][row] = a4.z;
            As[seg * 4 + 3][row] = a4.w;
        }
        {   // B tile 16x128
            int kk = t >> 4, nn = (t & 15) * 8;
            float4 b0 = *(const float4*)(&Bmat[(size_t)(k0 + kk) * 1024 + n0 + nn]);
            float4 b1 = *(const float4*)(&Bmat[(size_t)(k0 + kk) * 1024 + n0 + nn + 4]);
            *(float4*)&Bs[kk][nn]     = b0;
            *(float4*)&Bs[kk][nn + 4] = b1;
        }
        __syncthreads();
        #pragma unroll
        for (int k = 0; k < BK; ++k) {
            float4 a  = *(const float4*)&As[k][tm];
            float4 b0 = *(const float4*)&Bs[k][tn];
            float4 b1 = *(const float4*)&Bs[k][tn + 4];
            float av[4] = {a.x, a.y, a.z, a.w};
            float bv[8] = {b0.x, b0.y, b0.z, b0.w, b1.x, b1.y, b1.z, b1.w};
            #pragma unroll
            for (int i = 0; i < 4; ++i)
                #pragma unroll
                for (int j = 0; j < 8; ++j)
                    acc[i][j] += av[i] * bv[j];
        }
        __syncthreads();
    }
    #pragma unroll
    for (int i = 0; i < 4; ++i) {
        int m = m0 + tm + i;
        #pragma unroll
        for (int j = 0; j < 8; j += 4) {
            float4 o;
            o.x = acc[i][j + 0] + bP[dir * 1024 + n0 + tn + j + 0];
            o.y = acc[i][j + 1] + bP[dir * 1024 + n0 + tn + j + 1];
            o.z = acc[i][j + 2] + bP[dir * 1024 + n0 + tn + j + 2];
            o.w = acc[i][j + 3] + bP[dir * 1024 + n0 + tn + j + 3];
            *(float4*)&C[(size_t)m * 1024 + n0 + tn + j] = o;
        }
    }
}

// ---------------------------------------------------------------------------
// LSTM recurrence, LDS-resident f16 weights. R8: ALL cross-WG traffic uses
// RELAXED agent-scope atomics (sc-bit bypass to the coherence point, NO
// buffer_inv / wbl2 -- R7's acquire-per-poll invalidated the XCD L2 every
// ~300cy, evicting embproj and throttling the chip). Producer ordering via
// explicit s_waitcnt vmcnt(0) between h stores and the flag store; consumer
// via control dependence + compiler barrier.
// h16 LDS layout swizzled: [bat][par][slice(8)][20 u32] -- stride 20 puts the
// 8 kq2 slices on 8 distinct bank quads (R7's kq2*16 was 4-way conflicted).
// ---------------------------------------------------------------------------
__global__ __launch_bounds__(512) void lstm_lds3_kernel(
    const int* __restrict__ sentence,
    const float* __restrict__ embproj,
    const unsigned int* __restrict__ W16p,
    const float* __restrict__ WlinQ,
    unsigned int* __restrict__ hg,
    int* __restrict__ flags,
    float* __restrict__ emisP)
{
    extern __shared__ char smem[];
    uint4*        LW4  = (uint4*)smem;                        // 128 KB swizzled weights
    unsigned int* h16  = (unsigned int*)(smem + 131072);      // [bat][par][8][20] u32
    float*        part = (float*)(smem + 131072 + 2560);      // [bat][64][4] f32

    const int bx   = blockIdx.x;
    const int us   = bx >> 6;          // 0..3
    const int team = bx & 63;          // members bx = team + 64*us: same XCD mod 8
    const int dir  = team >> 5;
    const int bg   = team & 31;
    const int b0   = bg * 2;
    const int tid  = threadIdx.x;
    const int u_loc = tid >> 3;        // 0..63
    const int kq2   = tid & 7;         // 0..7
    const int wave  = tid >> 6;
    const int lane  = tid & 63;

    // ---- stage weights into LDS, swizzled (conflict-free, verified R7) ----
    {
        const uint4* Wsrc = (const uint4*)(W16p + ((size_t)(dir * 4 + us) << 15));
        #pragma unroll
        for (int i = 0; i < 16; ++i) {
            const int idx = i * 512 + tid;
            LW4[idx ^ ((idx >> 10) & 7)] = Wsrc[idx];
        }
    }
    if (tid < 640) h16[tid] = 0u;      // zero both parities incl. pads

    const float* EP = embproj + (size_t)dir * EPROJ_PER_DIR;
    const int fl_base = team * 8;
    unsigned int* hgT = hg + (size_t)team * 512;   // [q][par][bat][32] u32

    // act-wave persistent state (waves 0/1)
    const int bat = wave;              // meaningful for wave<2
    const int b = b0 + (wave < 2 ? bat : 0);
    const int* sent = sentence + (size_t)b * Ss;
    float c = 0.f;
    float4 wl = make_float4(0.f, 0.f, 0.f, 0.f);
    float4 ep = make_float4(0.f, 0.f, 0.f, 0.f);
    const int uact = us * 64 + lane;
    if (wave < 2) {
        wl = *(const float4*)&WlinQ[(dir * 256 + uact) * 4];
        const int pos0 = dir ? (Ss - 1) : 0;
        ep = *(const float4*)(EP + (size_t)sent[pos0] * 1024 + uact * 4);
    }
    const int di = us * 2 + dir;       // emission partial buffer index
    const int wbase = kq2 * 1024 + u_loc;   // uint4 idx of first weight (i=0)
    long budget = 200000000;           // bounded spin: wrong answer, not hang

    __syncthreads();

    for (int s = 0; s < Ss; ++s) {
        const int wr = s & 1, rd = wr ^ 1;
        const int pos = dir ? (Ss - 1 - s) : s;

        // ---- dot: 16 k-pairs x 4 gates x 2 batches; weights LDS (swizzled) ----
        {
            const int hbA = (0 * 2 + rd) * 160 + kq2 * 20;
            const int hbB = (1 * 2 + rd) * 160 + kq2 * 20;
            unsigned int hA[16], hB[16];
            #pragma unroll
            for (int r = 0; r < 4; ++r) {
                uint4 qa = *(const uint4*)&h16[hbA + r * 4];
                uint4 qb = *(const uint4*)&h16[hbB + r * 4];
                hA[r*4] = qa.x; hA[r*4+1] = qa.y; hA[r*4+2] = qa.z; hA[r*4+3] = qa.w;
                hB[r*4] = qb.x; hB[r*4+1] = qb.y; hB[r*4+2] = qb.z; hB[r*4+3] = qb.w;
            }
            float4 aA = make_float4(0.f,0.f,0.f,0.f), aB = make_float4(0.f,0.f,0.f,0.f);
            #pragma unroll
            for (int i = 0; i < 16; ++i) {
                const uint4 w = LW4[(wbase + i * 64) ^ kq2];
                aA.x = fdot2u(hA[i], w.x, aA.x);
                aA.y = fdot2u(hA[i], w.y, aA.y);
                aA.z = fdot2u(hA[i], w.z, aA.z);
                aA.w = fdot2u(hA[i], w.w, aA.w);
                aB.x = fdot2u(hB[i], w.x, aB.x);
                aB.y = fdot2u(hB[i], w.y, aB.y);
                aB.z = fdot2u(hB[i], w.z, aB.z);
                aB.w = fdot2u(hB[i], w.w, aB.w);
            }
            #pragma unroll
            for (int off = 4; off > 0; off >>= 1) {
                aA.x += __shfl_down(aA.x, off); aA.y += __shfl_down(aA.y, off);
                aA.z += __shfl_down(aA.z, off); aA.w += __shfl_down(aA.w, off);
                aB.x += __shfl_down(aB.x, off); aB.y += __shfl_down(aB.y, off);
                aB.z += __shfl_down(aB.z, off); aB.w += __shfl_down(aB.w, off);
            }
            if (kq2 == 0) {
                *(float4*)&part[(0 * 64 + u_loc) * 4] = aA;
                *(float4*)&part[(1 * 64 + u_loc) * 4] = aB;
            }
        }
        __syncthreads();   // b1: part[] ready

        if (wave < 2) {
            // ---- activation ----
            const float4 pp = *(const float4*)&part[(bat * 64 + lane) * 4];
            const float gi = pp.x + ep.x, gf = pp.y + ep.y,
                        gg = pp.z + ep.z, go = pp.w + ep.w;
            c = sigm(gf) * c + sigm(gi) * tanhf(gg);
            const float h = sigm(go) * tanhf(c);
            // ---- publish h first (shortest peer-visible latency) ----
            const float hn = __shfl_down(h, 1);
            if (!(lane & 1)) {
                union { _Float16 hh[2]; unsigned int u32; } pk;
                pk.hh[0] = (_Float16)h; pk.hh[1] = (_Float16)hn;
                const int kp   = us * 32 + (lane >> 1);        // k-pair index
                const int slic = kp >> 4, posn = kp & 15;
                h16[(bat * 2 + wr) * 160 + slic * 20 + posn] = pk.u32;
                __hip_atomic_store(&hgT[((us * 2 + wr) * 2 + bat) * 32 + (lane >> 1)],
                                   pk.u32, __ATOMIC_RELAXED, __HIP_MEMORY_SCOPE_AGENT);
            }
            asm volatile("s_waitcnt vmcnt(0)" ::: "memory");   // h stores done
            if (lane == 0)
                __hip_atomic_store(&flags[fl_base + us * 2 + bat], s + 1,
                                   __ATOMIC_RELAXED, __HIP_MEMORY_SCOPE_AGENT);
            // ---- fused emission (after flag: off the sync critical path) ----
            float4 em = make_float4(h * wl.x, h * wl.y, h * wl.z, h * wl.w);
            #pragma unroll
            for (int off = 32; off > 0; off >>= 1) {
                em.x += __shfl_down(em.x, off); em.y += __shfl_down(em.y, off);
                em.z += __shfl_down(em.z, off); em.w += __shfl_down(em.w, off);
            }
            if (lane == 0)
                *(float4*)&emisP[(((size_t)di * Ss + pos) * Bb + b) * 4] = em;
            if (s + 1 < Ss) {
                const int pn = dir ? (Ss - 2 - s) : (s + 1);
                ep = *(const float4*)(EP + (size_t)sent[pn] * 1024 + uact * 4);
            }
        } else if (wave == 7 && s + 1 < Ss) {
            // ---- import 3 peer quarters of h(s): relaxed polls, no cache ops ----
            if (lane < 6) {
                const int pi = lane >> 1;
                const int q  = pi + (pi >= us);
                const int* fp = &flags[fl_base + q * 2 + (lane & 1)];
                while (__hip_atomic_load(fp, __ATOMIC_RELAXED,
                                         __HIP_MEMORY_SCOPE_AGENT) < s + 1) {
                    __builtin_amdgcn_s_sleep(2);
                    if (--budget < 0) break;
                }
            }
            asm volatile("" ::: "memory");   // keep h loads below the poll
            const int bt = lane >> 5, idx32 = lane & 31;
            #pragma unroll
            for (int pi = 0; pi < 3; ++pi) {
                const int q = pi + (pi >= us);
                const unsigned int v = __hip_atomic_load(
                    &hgT[((q * 2 + wr) * 2 + bt) * 32 + idx32],
                    __ATOMIC_RELAXED, __HIP_MEMORY_SCOPE_AGENT);
                const int kp = q * 32 + idx32;
                h16[(bt * 2 + wr) * 160 + (kp >> 4) * 20 + (kp & 15)] = v;
            }
        }
        __syncthreads();   // b2: h16[wr] complete
    }
}

// ---------------------------------------------------------------------------
// merge 8 emission partials -> emis[s][b][4]
// ---------------------------------------------------------------------------
__global__ __launch_bounds__(256) void emis_merge_kernel(const float* __restrict__ emisP,
                                                         float* __restrict__ emis)
{
    const int i = blockIdx.x * 256 + threadIdx.x;   // < 131072
    float v = 0.f;
    #pragma unroll
    for (int d = 0; d < 8; ++d) v += emisP[(size_t)d * (Ss * Bb * 4) + i];
    emis[i] = v;
}

// ---------------------------------------------------------------------------
// Fused CRF + Viterbi tail. grid 8 x 64 threads.
// ---------------------------------------------------------------------------
__global__ __launch_bounds__(64) void tail_kernel(
    const float* __restrict__ emis,
    const float* __restrict__ blin, const float* __restrict__ start_t,
    const float* __restrict__ end_t, const float* __restrict__ trans,
    const int* __restrict__ tags, float* __restrict__ out_tags,
    float* __restrict__ out_loss)
{
    const int blk = blockIdx.x;
    const int t = threadIdx.x;
    const int b_loc = t >> 2, j = t & 3;
    const int base = t & ~3;

    if (blk < 4) {
        __shared__ unsigned char bp_sh[16][513][4];
        __shared__ unsigned char tag_sh[16][520];
        const int b = blk * 16 + b_loc;
        const float trj0 = trans[0*4+j], trj1 = trans[1*4+j],
                    trj2 = trans[2*4+j], trj3 = trans[3*4+j];
        const float blj = blin[j];
        float score = start_t[j] + emis[(size_t)b*4 + j] + blj;
        for (int s = 1; s < Ss; ++s) {
            const float e = emis[((size_t)s*Bb + b)*4 + j] + blj;
            const float s0 = __shfl(score, base+0), s1 = __shfl(score, base+1),
                        s2 = __shfl(score, base+2), s3 = __shfl(score, base+3);
            float best = s0 + trj0; int bi = 0;
            float v = s1 + trj1; if (v > best) { best = v; bi = 1; }
            v = s2 + trj2; if (v > best) { best = v; bi = 2; }
            v = s3 + trj3; if (v > best) { best = v; bi = 3; }
            score = best + e;
            bp_sh[b_loc][s][j] = (unsigned char)bi;
        }
        const float fv = score + end_t[j];
        const float f0 = __shfl(fv, base+0), f1 = __shfl(fv, base+1),
                    f2 = __shfl(fv, base+2), f3 = __shfl(fv, base+3);
        __syncthreads();
        if (j == 0) {   // backtrack (first-occurrence argmax, like jnp)
            float best = f0; int tag = 0;
            if (f1 > best) { best = f1; tag = 1; }
            if (f2 > best) { best = f2; tag = 2; }
            if (f3 > best) { best = f3; tag = 3; }
            tag_sh[b_loc][Ss-1] = (unsigned char)tag;
            for (int s = Ss - 1; s >= 1; --s) {
                tag = bp_sh[b_loc][s][tag];
                tag_sh[b_loc][s-1] = (unsigned char)tag;
            }
        }
        __syncthreads();
        for (int idx = t; idx < 16 * Ss; idx += 64) {
            const int bl = idx >> 9, s = idx & (Ss - 1);
            out_tags[(size_t)(blk*16 + bl) * Ss + s] = (float)tag_sh[bl][s];
        }
    } else {
        const int b = (blk - 4) * 16 + b_loc;
        const float trj0 = trans[0*4+j], trj1 = trans[1*4+j],
                    trj2 = trans[2*4+j], trj3 = trans[3*4+j];
        const float blj = blin[j];
        float alpha = start_t[j] + emis[(size_t)b*4 + j] + blj;
        for (int s = 1; s < Ss; ++s) {
            const float e = emis[((size_t)s*Bb + b)*4 + j] + blj;
            const float a0 = __shfl(alpha, base+0), a1 = __shfl(alpha, base+1),
                        a2 = __shfl(alpha, base+2), a3 = __shfl(alpha, base+3);
            const float x0 = a0 + trj0, x1 = a1 + trj1, x2 = a2 + trj2, x3 = a3 + trj3;
            const float m = fmaxf(fmaxf(x0, x1), fmaxf(x2, x3));
            alpha = m + logf(expf(x0-m) + expf(x1-m) + expf(x2-m) + expf(x3-m)) + e;
        }
        const float dv = alpha + end_t[j];
        const float d0 = __shfl(dv, base+0), d1 = __shfl(dv, base+1),
                    d2 = __shfl(dv, base+2), d3 = __shfl(dv, base+3);
        const float dm = fmaxf(fmaxf(d0, d1), fmaxf(d2, d3));
        const float denom = dm + logf(expf(d0-dm) + expf(d1-dm) + expf(d2-dm) + expf(d3-dm));

        const int lo = j * 128, hi = lo + 128;
        float num = 0.f;
        int tprev = (lo > 0) ? tags[(size_t)b*Ss + lo - 1] : 0;
        if (j == 0) num += start_t[tags[(size_t)b*Ss]];
        if (j == 3) num += end_t[tags[(size_t)b*Ss + Ss - 1]];
        for (int s = lo; s < hi; ++s) {
            const int tg = tags[(size_t)b*Ss + s];
            num += emis[((size_t)s*Bb + b)*4 + tg] + blin[tg];
            if (s > 0) num += trans[tprev*4 + tg];
            tprev = tg;
        }
        num += __shfl_xor(num, 1);
        num += __shfl_xor(num, 2);
        float lb = (j == 0) ? (denom - num) : 0.f;
        #pragma unroll
        for (int off = 32; off > 0; off >>= 1) lb += __shfl_down(lb, off);
        if (t == 0) atomicAdd(out_loss, lb);
    }
}

// ---------------------------------------------------------------------------
extern "C" void kernel_launch(void* const* d_in, const int* in_sizes, int n_in,
                              void* d_out, int out_size, void* d_ws, size_t ws_size,
                              hipStream_t stream)
{
    const int*   sentence = (const int*)d_in[0];
    const int*   tags     = (const int*)d_in[1];
    const float* emb      = (const float*)d_in[3];
    const float* Wih_f    = (const float*)d_in[4];
    const float* Whh_f    = (const float*)d_in[5];
    const float* b_f      = (const float*)d_in[6];
    const float* Wih_b    = (const float*)d_in[7];
    const float* Whh_b    = (const float*)d_in[8];
    const float* b_b      = (const float*)d_in[9];
    const float* Wlin     = (const float*)d_in[10];
    const float* blin     = (const float*)d_in[11];
    const float* start_t  = (const float*)d_in[12];
    const float* end_t    = (const float*)d_in[13];
    const float* trans    = (const float*)d_in[14];

    // workspace layout (floats)
    float*        embproj = (float*)d_ws;                      // 16,384,000
    float*        WihP    = embproj + 2 * EPROJ_PER_DIR;       // 524,288 (reused)
    unsigned int* W16p    = (unsigned int*)(WihP + 2 * WMAT_PER_DIR);  // 262,144 u32
    float*        bP      = (float*)(W16p + 262144);           // 2048
    float*        WlinQ   = bP + 2048;                         // 2048
    float*        emisP   = WlinQ + 2048;                      // 8*512*64*4
    float*        emis    = emisP + 8 * Ss * Bb * 4;           // 131,072

    // WihP region dead after the GEMM -> flags + h exchange
    int*          flags  = (int*)WihP;                         // 512 ints
    unsigned int* hg     = (unsigned int*)(WihP + 1024);       // 64*512 u32

    prep_kernel<<<2048, 256, 0, stream>>>(Wih_f, Whh_f, b_f, Wih_b, Whh_b, b_b, Wlin,
                                          WihP, W16p, bP, WlinQ);
    dim3 gg(Vv / BM, 1024 / BN, 2);
    embproj_gemm<<<gg, 256, 0, stream>>>(emb, WihP, bP, embproj);

    hipMemsetAsync(flags, 0, 512 * sizeof(int), stream);

    const int* k_sent = sentence;
    const float* k_ep = embproj;
    const unsigned int* k_w = W16p;
    const float* k_wlin = WlinQ;
    unsigned int* k_hg = hg;
    int* k_fl = flags;
    float* k_em = emisP;
    void* args[] = { (void*)&k_sent, (void*)&k_ep, (void*)&k_w, (void*)&k_wlin,
                     (void*)&k_hg, (void*)&k_fl, (void*)&k_em };
    hipLaunchCooperativeKernel((const void*)lstm_lds3_kernel, dim3(256), dim3(512),
                               args, 131072 + 2560 + 2048, stream);

    emis_merge_kernel<<<512, 256, 0, stream>>>(emisP, emis);

    float* out = (float*)d_out;
    float* out_loss = out + Bb * Ss;
    hipMemsetAsync(out_loss, 0, sizeof(float), stream);
    tail_kernel<<<8, 64, 0, stream>>>(emis, blin, start_t, end_t, trans,
                                      tags, out, out_loss);
}

// Round 11
// 2032.681 us; speedup vs baseline: 14.2157x; 1.0003x over previous
//
#include <hip/hip_runtime.h>
#include <math.h>

// Problem constants
#define Vv 8000
#define Ee 256
#define Hh 256
#define Tt 4
#define Bb 64
#define Ss 512

#define EPROJ_PER_DIR (Vv * 1024)   // 8,192,000 floats per direction
#define WMAT_PER_DIR  (Ee * 1024)   // 262,144 floats per direction

__device__ __forceinline__ float sigm(float x) { return 1.f / (1.f + expf(-x)); }

typedef _Float16 half2v __attribute__((ext_vector_type(2)));

__device__ __forceinline__ float fdot2u(unsigned int a, unsigned int b, float c) {
    half2v ha = __builtin_bit_cast(half2v, a);
    half2v hb = __builtin_bit_cast(half2v, b);
#if __has_builtin(__builtin_amdgcn_fdot2)
    return __builtin_amdgcn_fdot2(ha, hb, c, false);
#else
    return c + (float)ha[0] * (float)hb[0] + (float)ha[1] * (float)hb[1];
#endif
}

// ---------------------------------------------------------------------------
// prep: repack weights.
//   WihP [dir][e][j']  j' = u*4+g <-> gate-row g*256+u    (GEMM B-matrix)
//   W16L [dir][us][i][tid][g] u32: LINEAR LDS image -- LSTM thread
//        tid = u_loc*8+kq2 reads LW4[i*512+tid] (64 consecutive uint4 per
//        wave instruction -> conflict-free, 2 lanes/bank).
//        value.g = f16x2 of Whh[g*256 + us*64+u_loc][2kp..2kp+1], kp = kq2*16+i
//   bP   [dir][j']
//   WlinQ[dir][u][t] float4/u = Wlin[t][dir*256+u]        (emission)
// ---------------------------------------------------------------------------
__global__ void prep_kernel(const float* __restrict__ Wih_f, const float* __restrict__ Whh_f,
                            const float* __restrict__ b_f,
                            const float* __restrict__ Wih_b, const float* __restrict__ Whh_b,
                            const float* __restrict__ b_b,
                            const float* __restrict__ Wlin,
                            float* __restrict__ WihP, unsigned int* __restrict__ W16L,
                            float* __restrict__ bP, float* __restrict__ WlinQ)
{
    int tid = blockIdx.x * blockDim.x + threadIdx.x;   // [0, 2*262144)
    int dir = tid >> 18;
    int r   = tid & 262143;
    int k   = r >> 10;        // 0..255
    int jp  = r & 1023;       // j'
    int u   = jp >> 2;
    int g   = jp & 3;
    int row = g * 256 + u;    // original gate row
    const float* Wih = dir ? Wih_b : Wih_f;
    const float* Whh = dir ? Whh_b : Whh_f;
    const float* bv  = dir ? b_b   : b_f;
    WihP[dir * WMAT_PER_DIR + k * 1024 + jp] = Wih[row * 256 + k];
    if (!(k & 1)) {
        int kp = k >> 1;                 // 0..127
        int us = u >> 6, u_loc = u & 63;
        int kq2 = kp >> 4, i = kp & 15;
        union { _Float16 h[2]; unsigned int u32; } pk;
        pk.h[0] = (_Float16)Whh[row * 256 + k];
        pk.h[1] = (_Float16)Whh[row * 256 + k + 1];
        W16L[((dir * 4 + us) * 8192 + i * 512 + u_loc * 8 + kq2) * 4 + g] = pk.u32;
    }
    if (r < 1024) {
        bP[dir * 1024 + jp] = bv[row];
        int uu = r >> 2, tt = r & 3;
        WlinQ[(dir * 256 + uu) * 4 + tt] = Wlin[tt * (2 * Hh) + dir * 256 + uu];
    }
}

// ---------------------------------------------------------------------------
// embproj GEMM: embproj[dir][v][j'] = sum_e emb[v][e]*WihP[dir][e][j'] + bP[dir][j']
// ---------------------------------------------------------------------------
#define BM 64
#define BN 128
#define BK 16
__global__ __launch_bounds__(256) void embproj_gemm(const float* __restrict__ emb,
                                                    const float* __restrict__ WihP,
                                                    const float* __restrict__ bP,
                                                    float* __restrict__ embproj)
{
    int dir = blockIdx.z;
    const float* Bmat = WihP + dir * WMAT_PER_DIR;
    float* C = embproj + (size_t)dir * EPROJ_PER_DIR;
    int m0 = blockIdx.x * BM;
    int n0 = blockIdx.y * BN;

    __shared__ float As[BK][BM];
    __shared__ float Bs[BK][BN];

    int t = threadIdx.x;
    int tm = (t & 15) * 4;
    int tn = (t >> 4) * 8;
    float acc[4][8];
    #pragma unroll
    for (int i = 0; i < 4; ++i)
        #pragma unroll
        for (int j = 0; j < 8; ++j) acc[i][j] = 0.f;

    for (int k0 = 0; k0 < Ee; k0 += BK) {
        {   // A tile 64x16
            int row = t >> 2, seg = t & 3;
            float4 a4 = *(const float4*)(&emb[(size_t)(m0 + row) * Ee + k0 + seg * 4]);
            As[seg * 4 + 0][row] = a4.x;
            As[seg * 4 + 1][row] = a4.y;
            As[seg * 4 + 2][row] = a4.z;
            As[seg * 4 + 3][row] = a4.w;
        }
        {   // B tile 16x128
            int kk = t >> 4, nn = (t & 15) * 8;
            float4 b0 = *(const float4*)(&Bmat[(size_t)(k0 + kk) * 1024 + n0 + nn]);
            float4 b1 = *(const float4*)(&Bmat[(size_t)(k0 + kk) * 1024 + n0 + nn + 4]);
            *(float4*)&Bs[kk][nn]     = b0;
            *(float4*)&Bs[kk][nn + 4] = b1;
        }
        __syncthreads();
        #pragma unroll
        for (int k = 0; k < BK; ++k) {
            float4 a  = *(const float4*)&As[k][tm];
            float4 b0 = *(const float4*)&Bs[k][tn];
            float4 b1 = *(const float4*)&Bs[k][tn + 4];
            float av[4] = {a.x, a.y, a.z, a.w};
            float bv[8] = {b0.x, b0.y, b0.z, b0.w, b1.x, b1.y, b1.z, b1.w};
            #pragma unroll
            for (int i = 0; i < 4; ++i)
                #pragma unroll
                for (int j = 0; j < 8; ++j)
                    acc[i][j] += av[i] * bv[j];
        }
        __syncthreads();
    }
    #pragma unroll
    for (int i = 0; i < 4; ++i) {
        int m = m0 + tm + i;
        #pragma unroll
        for (int j = 0; j < 8; j += 4) {
            float4 o;
            o.x = acc[i][j + 0] + bP[dir * 1024 + n0 + tn + j + 0];
            o.y = acc[i][j + 1] + bP[dir * 1024 + n0 + tn + j + 1];
            o.z = acc[i][j + 2] + bP[dir * 1024 + n0 + tn + j + 2];
            o.w = acc[i][j + 3] + bP[dir * 1024 + n0 + tn + j + 3];
            *(float4*)&C[(size_t)m * 1024 + n0 + tn + j] = o;
        }
    }
}

// ---------------------------------------------------------------------------
// LSTM recurrence. R8 structure + sync (proven stable 1780us): relaxed agent
// atomics only, producer ordering via s_waitcnt vmcnt(0), wave-7-only import
// with 6 polling lanes + s_sleep. R10/R11 change: weights pre-permuted LINEAR
// in LDS -> dot reads LW4[i*512+tid], conflict-free. R11 hardening: hg+flags
// fully zeroed before launch (failed poll -> h=0, finite-wrong, not NaN);
// budget 30M with s_sleep(4) (bounded ~7s worst, instant when healthy).
// ---------------------------------------------------------------------------
__global__ __launch_bounds__(512) void lstm_lds5_kernel(
    const int* __restrict__ sentence,
    const float* __restrict__ embproj,
    const unsigned int* __restrict__ W16L,
    const float* __restrict__ WlinQ,
    unsigned int* __restrict__ hg,
    int* __restrict__ flags,
    float* __restrict__ emisP)
{
    extern __shared__ char smem[];
    uint4*        LW4  = (uint4*)smem;                        // 128 KB weights (linear)
    unsigned int* h16  = (unsigned int*)(smem + 131072);      // [bat][par][8][20] u32
    float*        part = (float*)(smem + 131072 + 2560);      // [bat][64][4] f32

    const int bx   = blockIdx.x;
    const int us   = bx >> 6;          // 0..3
    const int team = bx & 63;          // members bx = team + 64*q: same XCD mod 8
    const int dir  = team >> 5;
    const int bg   = team & 31;
    const int b0   = bg * 2;
    const int tid  = threadIdx.x;
    const int kq2   = tid & 7;         // 0..7 (32-k slice)
    const int wave  = tid >> 6;
    const int lane  = tid & 63;

    // ---- stage weights into LDS (linear, coalesced, conflict-free reads) ----
    {
        const uint4* Wsrc = (const uint4*)(W16L + ((size_t)(dir * 4 + us) << 15));
        #pragma unroll
        for (int i = 0; i < 16; ++i)
            LW4[i * 512 + tid] = Wsrc[i * 512 + tid];
    }
    if (tid < 640) h16[tid] = 0u;      // zero both parities incl. pads

    const float* EP = embproj + (size_t)dir * EPROJ_PER_DIR;
    const int fl_base = team * 8;
    unsigned int* hgT = hg + (size_t)team * 512;   // [q][par][bat][32] u32

    // act-wave persistent state (waves 0/1)
    const int bat = wave;              // meaningful for wave<2
    const int b = b0 + (wave < 2 ? bat : 0);
    const int* sent = sentence + (size_t)b * Ss;
    float c = 0.f;
    float4 wl = make_float4(0.f, 0.f, 0.f, 0.f);
    float4 ep = make_float4(0.f, 0.f, 0.f, 0.f);
    const int uact = us * 64 + lane;
    if (wave < 2) {
        wl = *(const float4*)&WlinQ[(dir * 256 + uact) * 4];
        const int pos0 = dir ? (Ss - 1) : 0;
        ep = *(const float4*)(EP + (size_t)sent[pos0] * 1024 + uact * 4);
    }
    const int di = us * 2 + dir;       // emission partial buffer index
    long budget = 30000000;            // bounded spin: wrong answer, not hang

    __syncthreads();

    for (int s = 0; s < Ss; ++s) {
        const int wr = s & 1, rd = wr ^ 1;
        const int pos = dir ? (Ss - 1 - s) : s;

        // ---- dot: 16 k-pairs x 4 gates x 2 batches; LINEAR weight reads ----
        {
            const int hbA = (0 * 2 + rd) * 160 + kq2 * 20;
            const int hbB = (1 * 2 + rd) * 160 + kq2 * 20;
            unsigned int hA[16], hB[16];
            #pragma unroll
            for (int r = 0; r < 4; ++r) {
                uint4 qa = *(const uint4*)&h16[hbA + r * 4];
                uint4 qb = *(const uint4*)&h16[hbB + r * 4];
                hA[r*4] = qa.x; hA[r*4+1] = qa.y; hA[r*4+2] = qa.z; hA[r*4+3] = qa.w;
                hB[r*4] = qb.x; hB[r*4+1] = qb.y; hB[r*4+2] = qb.z; hB[r*4+3] = qb.w;
            }
            float4 aA = make_float4(0.f,0.f,0.f,0.f), aB = make_float4(0.f,0.f,0.f,0.f);
            #pragma unroll
            for (int i = 0; i < 16; ++i) {
                const uint4 w = LW4[i * 512 + tid];
                aA.x = fdot2u(hA[i], w.x, aA.x);
                aA.y = fdot2u(hA[i], w.y, aA.y);
                aA.z = fdot2u(hA[i], w.z, aA.z);
                aA.w = fdot2u(hA[i], w.w, aA.w);
                aB.x = fdot2u(hB[i], w.x, aB.x);
                aB.y = fdot2u(hB[i], w.y, aB.y);
                aB.z = fdot2u(hB[i], w.z, aB.z);
                aB.w = fdot2u(hB[i], w.w, aB.w);
            }
            #pragma unroll
            for (int off = 4; off > 0; off >>= 1) {
                aA.x += __shfl_down(aA.x, off); aA.y += __shfl_down(aA.y, off);
                aA.z += __shfl_down(aA.z, off); aA.w += __shfl_down(aA.w, off);
                aB.x += __shfl_down(aB.x, off); aB.y += __shfl_down(aB.y, off);
                aB.z += __shfl_down(aB.z, off); aB.w += __shfl_down(aB.w, off);
            }
            if (kq2 == 0) {
                const int u_loc = tid >> 3;
                *(float4*)&part[(0 * 64 + u_loc) * 4] = aA;
                *(float4*)&part[(1 * 64 + u_loc) * 4] = aB;
            }
        }
        __syncthreads();   // b1: part[] ready

        if (wave < 2) {
            // ---- activation ----
            const float4 pp = *(const float4*)&part[(bat * 64 + lane) * 4];
            const float gi = pp.x + ep.x, gf = pp.y + ep.y,
                        gg = pp.z + ep.z, go = pp.w + ep.w;
            c = sigm(gf) * c + sigm(gi) * tanhf(gg);
            const float h = sigm(go) * tanhf(c);
            // ---- publish h first (shortest peer-visible latency) ----
            const float hn = __shfl_down(h, 1);
            if (!(lane & 1)) {
                union { _Float16 hh[2]; unsigned int u32; } pk;
                pk.hh[0] = (_Float16)h; pk.hh[1] = (_Float16)hn;
                const int kp   = us * 32 + (lane >> 1);        // k-pair index
                const int slic = kp >> 4, posn = kp & 15;
                h16[(bat * 2 + wr) * 160 + slic * 20 + posn] = pk.u32;
                __hip_atomic_store(&hgT[((us * 2 + wr) * 2 + bat) * 32 + (lane >> 1)],
                                   pk.u32, __ATOMIC_RELAXED, __HIP_MEMORY_SCOPE_AGENT);
            }
            asm volatile("s_waitcnt vmcnt(0)" ::: "memory");   // h stores done
            if (lane == 0)
                __hip_atomic_store(&flags[fl_base + us * 2 + bat], s + 1,
                                   __ATOMIC_RELAXED, __HIP_MEMORY_SCOPE_AGENT);
            // ---- fused emission (after flag: off the sync critical path) ----
            float4 em = make_float4(h * wl.x, h * wl.y, h * wl.z, h * wl.w);
            #pragma unroll
            for (int off = 32; off > 0; off >>= 1) {
                em.x += __shfl_down(em.x, off); em.y += __shfl_down(em.y, off);
                em.z += __shfl_down(em.z, off); em.w += __shfl_down(em.w, off);
            }
            if (lane == 0)
                *(float4*)&emisP[(((size_t)di * Ss + pos) * Bb + b) * 4] = em;
            if (s + 1 < Ss) {
                const int pn = dir ? (Ss - 2 - s) : (s + 1);
                ep = *(const float4*)(EP + (size_t)sent[pn] * 1024 + uact * 4);
            }
        } else if (wave == 7 && s + 1 < Ss) {
            // ---- import 3 peer quarters of h(s): relaxed polls, no cache ops ----
            if (lane < 6) {
                const int pi = lane >> 1;
                const int q  = pi + (pi >= us);
                const int* fp = &flags[fl_base + q * 2 + (lane & 1)];
                while (__hip_atomic_load(fp, __ATOMIC_RELAXED,
                                         __HIP_MEMORY_SCOPE_AGENT) < s + 1) {
                    __builtin_amdgcn_s_sleep(4);
                    if (--budget < 0) break;
                }
            }
            asm volatile("" ::: "memory");   // keep h loads below the poll
            const int bt = lane >> 5, idx32 = lane & 31;
            #pragma unroll
            for (int pi = 0; pi < 3; ++pi) {
                const int q = pi + (pi >= us);
                const unsigned int v = __hip_atomic_load(
                    &hgT[((q * 2 + wr) * 2 + bt) * 32 + idx32],
                    __ATOMIC_RELAXED, __HIP_MEMORY_SCOPE_AGENT);
                const int kp = q * 32 + idx32;
                h16[(bt * 2 + wr) * 160 + (kp >> 4) * 20 + (kp & 15)] = v;
            }
        }
        __syncthreads();   // b2: h16[wr] complete
    }
}

// ---------------------------------------------------------------------------
// merge 8 emission partials -> emis[s][b][4]
// ---------------------------------------------------------------------------
__global__ __launch_bounds__(256) void emis_merge_kernel(const float* __restrict__ emisP,
                                                         float* __restrict__ emis)
{
    const int i = blockIdx.x * 256 + threadIdx.x;   // < 131072
    float v = 0.f;
    #pragma unroll
    for (int d = 0; d < 8; ++d) v += emisP[(size_t)d * (Ss * Bb * 4) + i];
    emis[i] = v;
}

// ---------------------------------------------------------------------------
// Fused CRF + Viterbi tail. grid 8 x 64 threads.
// ---------------------------------------------------------------------------
__global__ __launch_bounds__(64) void tail_kernel(
    const float* __restrict__ emis,
    const float* __restrict__ blin, const float* __restrict__ start_t,
    const float* __restrict__ end_t, const float* __restrict__ trans,
    const int* __restrict__ tags, float* __restrict__ out_tags,
    float* __restrict__ out_loss)
{
    const int blk = blockIdx.x;
    const int t = threadIdx.x;
    const int b_loc = t >> 2, j = t & 3;
    const int base = t & ~3;

    if (blk < 4) {
        __shared__ unsigned char bp_sh[16][513][4];
        __shared__ unsigned char tag_sh[16][520];
        const int b = blk * 16 + b_loc;
        const float trj0 = trans[0*4+j], trj1 = trans[1*4+j],
                    trj2 = trans[2*4+j], trj3 = trans[3*4+j];
        const float blj = blin[j];
        float score = start_t[j] + emis[(size_t)b*4 + j] + blj;
        for (int s = 1; s < Ss; ++s) {
            const float e = emis[((size_t)s*Bb + b)*4 + j] + blj;
            const float s0 = __shfl(score, base+0), s1 = __shfl(score, base+1),
                        s2 = __shfl(score, base+2), s3 = __shfl(score, base+3);
            float best = s0 + trj0; int bi = 0;
            float v = s1 + trj1; if (v > best) { best = v; bi = 1; }
            v = s2 + trj2; if (v > best) { best = v; bi = 2; }
            v = s3 + trj3; if (v > best) { best = v; bi = 3; }
            score = best + e;
            bp_sh[b_loc][s][j] = (unsigned char)bi;
        }
        const float fv = score + end_t[j];
        const float f0 = __shfl(fv, base+0), f1 = __shfl(fv, base+1),
                    f2 = __shfl(fv, base+2), f3 = __shfl(fv, base+3);
        __syncthreads();
        if (j == 0) {   // backtrack (first-occurrence argmax, like jnp)
            float best = f0; int tag = 0;
            if (f1 > best) { best = f1; tag = 1; }
            if (f2 > best) { best = f2; tag = 2; }
            if (f3 > best) { best = f3; tag = 3; }
            tag_sh[b_loc][Ss-1] = (unsigned char)tag;
            for (int s = Ss - 1; s >= 1; --s) {
                tag = bp_sh[b_loc][s][tag];
                tag_sh[b_loc][s-1] = (unsigned char)tag;
            }
        }
        __syncthreads();
        for (int idx = t; idx < 16 * Ss; idx += 64) {
            const int bl = idx >> 9, s = idx & (Ss - 1);
            out_tags[(size_t)(blk*16 + bl) * Ss + s] = (float)tag_sh[bl][s];
        }
    } else {
        const int b = (blk - 4) * 16 + b_loc;
        const float trj0 = trans[0*4+j], trj1 = trans[1*4+j],
                    trj2 = trans[2*4+j], trj3 = trans[3*4+j];
        const float blj = blin[j];
        float alpha = start_t[j] + emis[(size_t)b*4 + j] + blj;
        for (int s = 1; s < Ss; ++s) {
            const float e = emis[((size_t)s*Bb + b)*4 + j] + blj;
            const float a0 = __shfl(alpha, base+0), a1 = __shfl(alpha, base+1),
                        a2 = __shfl(alpha, base+2), a3 = __shfl(alpha, base+3);
            const float x0 = a0 + trj0, x1 = a1 + trj1, x2 = a2 + trj2, x3 = a3 + trj3;
            const float m = fmaxf(fmaxf(x0, x1), fmaxf(x2, x3));
            alpha = m + logf(expf(x0-m) + expf(x1-m) + expf(x2-m) + expf(x3-m)) + e;
        }
        const float dv = alpha + end_t[j];
        const float d0 = __shfl(dv, base+0), d1 = __shfl(dv, base+1),
                    d2 = __shfl(dv, base+2), d3 = __shfl(dv, base+3);
        const float dm = fmaxf(fmaxf(d0, d1), fmaxf(d2, d3));
        const float denom = dm + logf(expf(d0-dm) + expf(d1-dm) + expf(d2-dm) + expf(d3-dm));

        const int lo = j * 128, hi = lo + 128;
        float num = 0.f;
        int tprev = (lo > 0) ? tags[(size_t)b*Ss + lo - 1] : 0;
        if (j == 0) num += start_t[tags[(size_t)b*Ss]];
        if (j == 3) num += end_t[tags[(size_t)b*Ss + Ss - 1]];
        for (int s = lo; s < hi; ++s) {
            const int tg = tags[(size_t)b*Ss + s];
            num += emis[((size_t)s*Bb + b)*4 + tg] + blin[tg];
            if (s > 0) num += trans[tprev*4 + tg];
            tprev = tg;
        }
        num += __shfl_xor(num, 1);
        num += __shfl_xor(num, 2);
        float lb = (j == 0) ? (denom - num) : 0.f;
        #pragma unroll
        for (int off = 32; off > 0; off >>= 1) lb += __shfl_down(lb, off);
        if (t == 0) atomicAdd(out_loss, lb);
    }
}

// ---------------------------------------------------------------------------
extern "C" void kernel_launch(void* const* d_in, const int* in_sizes, int n_in,
                              void* d_out, int out_size, void* d_ws, size_t ws_size,
                              hipStream_t stream)
{
    const int*   sentence = (const int*)d_in[0];
    const int*   tags     = (const int*)d_in[1];
    const float* emb      = (const float*)d_in[3];
    const float* Wih_f    = (const float*)d_in[4];
    const float* Whh_f    = (const float*)d_in[5];
    const float* b_f      = (const float*)d_in[6];
    const float* Wih_b    = (const float*)d_in[7];
    const float* Whh_b    = (const float*)d_in[8];
    const float* b_b      = (const float*)d_in[9];
    const float* Wlin     = (const float*)d_in[10];
    const float* blin     = (const float*)d_in[11];
    const float* start_t  = (const float*)d_in[12];
    const float* end_t    = (const float*)d_in[13];
    const float* trans    = (const float*)d_in[14];

    // workspace layout (floats)
    float*        embproj = (float*)d_ws;                      // 16,384,000
    float*        WihP    = embproj + 2 * EPROJ_PER_DIR;       // 524,288 (reused)
    unsigned int* W16L    = (unsigned int*)(WihP + 2 * WMAT_PER_DIR);  // 262,144 u32
    float*        bP      = (float*)(W16L + 262144);           // 2048
    float*        WlinQ   = bP + 2048;                         // 2048
    float*        emisP   = WlinQ + 2048;                      // 8*512*64*4
    float*        emis    = emisP + 8 * Ss * Bb * 4;           // 131,072

    // WihP region dead after the GEMM -> flags + h exchange
    int*          flags  = (int*)WihP;                         // 512 ints
    unsigned int* hg     = (unsigned int*)(WihP + 1024);       // 64*512 u32

    prep_kernel<<<2048, 256, 0, stream>>>(Wih_f, Whh_f, b_f, Wih_b, Whh_b, b_b, Wlin,
                                          WihP, W16L, bP, WlinQ);
    dim3 gg(Vv / BM, 1024 / BN, 2);
    embproj_gemm<<<gg, 256, 0, stream>>>(emb, WihP, bP, embproj);

    // zero flags + gap + hg (33,792 ints): a budget-expired poll then reads
    // h = 0 (finite-wrong, diagnosable) instead of stale-float NaN f16.
    hipMemsetAsync(flags, 0, 33792 * sizeof(int), stream);

    const int* k_sent = sentence;
    const float* k_ep = embproj;
    const unsigned int* k_w = W16L;
    const float* k_wlin = WlinQ;
    unsigned int* k_hg = hg;
    int* k_fl = flags;
    float* k_em = emisP;
    void* args[] = { (void*)&k_sent, (void*)&k_ep, (void*)&k_w, (void*)&k_wlin,
                     (void*)&k_hg, (void*)&k_fl, (void*)&k_em };
    hipLaunchCooperativeKernel((const void*)lstm_lds5_kernel, dim3(256), dim3(512),
                               args, 131072 + 2560 + 2048, stream);

    emis_merge_kernel<<<512, 256, 0, stream>>>(emisP, emis);

    float* out = (float*)d_out;
    float* out_loss = out + Bb * Ss;
    hipMemsetAsync(out_loss, 0, sizeof(float), stream);
    tail_kernel<<<8, 64, 0, stream>>>(emis, blin, start_t, end_t, trans,
                                      tags, out, out_loss);
}